// Round 8
// baseline (162.146 us; speedup 1.0000x reference)
//
#include <hip/hip_runtime.h>

#define B_ 4
#define N_ 16384
#define D_ 64
#define H_ 8
#define E_ 512
#define NCHUNK 32
#define NTILES (N_ / 64)

typedef __attribute__((ext_vector_type(8))) short short8;
typedef __attribute__((ext_vector_type(4))) float f32x4;
typedef __attribute__((ext_vector_type(2))) unsigned int uint32x2;

// f32 -> bf16 (RNE), scalar path (prep kernels only)
__device__ __forceinline__ unsigned short f2b(float f) {
    unsigned u = __float_as_uint(f);
    return (unsigned short)((u + 0x7fffu + ((u >> 16) & 1u)) >> 16);
}

// packed f32x2 -> bf16x2 (hardware RNE): lo16 = cvt(a), hi16 = cvt(b)
__device__ __forceinline__ unsigned cvtpk(float a, float b) {
    unsigned r;
    asm("v_cvt_pk_bf16_f32 %0, %1, %2" : "=v"(r) : "v"(a), "v"(b));
    return r;
}

// 16-lane sum via VALU DPP butterfly (no DS pipe)
template<int CTRL>
__device__ __forceinline__ float dppadd(float x) {
    int y = __builtin_amdgcn_update_dpp(0, __float_as_int(x), CTRL, 0xF, 0xF, true);
    return x + __int_as_float(y);
}
__device__ __forceinline__ float rowsum16(float x) {
    x = dppadd<0xB1>(x);    // quad_perm xor1
    x = dppadd<0x4E>(x);    // quad_perm xor2
    x = dppadd<0x141>(x);   // row_half_mirror
    x = dppadd<0x140>(x);   // row_mirror
    return x;
}

// ---------------------------------------------------------------------------
// k_prep: fused {pack Wq/Wk/Wv blobs | pack x blob}.
//   bid [0,384):  W blobs — per head [fr=nt*2+half][lane][e] u16 (8KB/head);
//                 element = W[kin][h*64+feat]; feat=nt*16+(lane&15),
//                 kin = half*32 + (lane>>4)*8 + e.
//   bid [384,2432): x blob — ((b*1024+tb)*2+fr)*512 + lane*8 + e with
//                 element = x[b][tb*16+(lane&15)][fr*32+(lane>>4)*8+e].
// ---------------------------------------------------------------------------
__global__ __launch_bounds__(256) void k_prep(
    const float* __restrict__ x,
    const float* __restrict__ Wq, const float* __restrict__ Wk,
    const float* __restrict__ Wv,
    unsigned short* __restrict__ WqB, unsigned short* __restrict__ WkB,
    unsigned short* __restrict__ WvB,
    unsigned short* __restrict__ xblob)
{
    const int bid = blockIdx.x, tid = threadIdx.x;
    if (bid < 384) {
        int mat = bid >> 7, sub = bid & 127;
        const float* src = (mat == 0) ? Wq : (mat == 1) ? Wk : Wv;
        unsigned short* dst = (mat == 0) ? WqB : (mat == 1) ? WkB : WvB;
        int id = sub * 256 + tid;          // 0..32767
        int kin = id >> 9, f = id & 511;
        int h = f >> 6, feat = f & 63;
        int nt = feat >> 4, cc = feat & 15;
        int half = kin >> 5, qd = (kin >> 3) & 3, e = kin & 7;
        dst[(size_t)h * 4096 + (((nt * 2 + half) * 64 + qd * 16 + cc) * 8) + e]
            = f2b(src[id]);
        return;
    }
    int idx = (bid - 384) * 256 + tid;     // 0..524287
    int lane = idx & 63, fr = (idx >> 6) & 1, tb = (idx >> 7) & 1023, b = idx >> 17;
    int cc = lane & 15, qd = lane >> 4;
    const float* src = &x[((size_t)b * N_ + tb * 16 + cc) * 64 + fr * 32 + qd * 8];
    float4 v0 = *(const float4*)src;
    float4 v1 = *(const float4*)(src + 4);
    ushort4 u0, u1;
    u0.x = f2b(v0.x); u0.y = f2b(v0.y); u0.z = f2b(v0.z); u0.w = f2b(v0.w);
    u1.x = f2b(v1.x); u1.y = f2b(v1.y); u1.z = f2b(v1.z); u1.w = f2b(v1.w);
    *(ushort4*)&xblob[(size_t)idx * 8]     = u0;
    *(ushort4*)&xblob[(size_t)idx * 8 + 4] = u1;
}

// ---------------------------------------------------------------------------
// Kernel 1 (MFMA): k,v projection + LN + RoPE(k) + kv partial accumulation.
// grid (NCHUNK=32, H, B) = 1024 blocks.
// R7 showed residency pinned at 2 blocks/CU by per-block resources (2x grid,
// same dur, same 16% occupancy). Fix: W fragments move from 64 VGPRs to LDS
// (staged once; per-tile ds_read_b128 frag loads are conflict-free and are
// INTENDED per-iteration ops, so the R4/R6 remat-from-HBM bug has no target).
// Single-buffered kbuf/vbuf (2 barriers/tile). LDS 34.8KB, regs ~110 under
// the (256,4) 128-cap -> 4 blocks/CU = 4 waves/SIMD, one grid round.
// ---------------------------------------------------------------------------
__global__ __launch_bounds__(256, 4) void k_kv(
    const unsigned short* __restrict__ xblob,
    const float* __restrict__ pos,
    const unsigned short* __restrict__ WkB,
    const unsigned short* __restrict__ WvB,
    float* __restrict__ kv_part)
{
    const int b = blockIdx.z, h = blockIdx.y, chunk = blockIdx.x;
    const int tid  = threadIdx.x;
    const int lane = tid & 63;
    const int w    = tid >> 6;        // wave id 0..3
    const int c    = lane & 15;
    const int quad = lane >> 4;
    const int m0   = w * 16;          // wave's 16-row band

    __shared__ unsigned short kbuf[64 * 72];   // k bf16 [feat][tok]  (9.2 KB)
    __shared__ unsigned short vbuf[64 * 72];   // v bf16 [feat][tok]  (9.2 KB)
    __shared__ unsigned short wkl[4096];       // Wk frag blob, head h (8 KB)
    __shared__ unsigned short wvl[4096];       // Wv frag blob, head h (8 KB)

    // ---- stage W blobs to LDS once (coop copy, already bf16 frag layout) ----
    {
        const float4* srcK = (const float4*)(WkB + (size_t)h * 4096);
        const float4* srcV = (const float4*)(WvB + (size_t)h * 4096);
        float4* dstK = (float4*)wkl;
        float4* dstV = (float4*)wvl;
        #pragma unroll
        for (int i = 0; i < 2; ++i) {       // 512 float4 per blob
            dstK[tid + i * 256] = srcK[tid + i * 256];
            dstV[tid + i * 256] = srcV[tid + i * 256];
        }
    }

    const float invf_lo = exp2f(-0.4152410118609203f * (float)c);  // 10000^(-c/32)
    const float invf_hi = invf_lo * 0.01f;                          // 10000^(-(16+c)/32)

    f32x4 akv[4];
    #pragma unroll
    for (int nt = 0; nt < 4; ++nt) akv[nt] = (f32x4){0.f, 0.f, 0.f, 0.f};

    // ---- prologue: first tile's A-frags + pos ----
    short8 a0, a1;
    float tp[4];
    {
        int tb = chunk * 4 + w;
        const unsigned short* xb = xblob + (size_t)((b * 1024 + tb) * 2) * 512 + lane * 8;
        a0 = *(const short8*)&xb[0];
        a1 = *(const short8*)&xb[512];
        #pragma unroll
        for (int r = 0; r < 4; ++r)
            tp[r] = pos[(size_t)b * N_ + chunk * 64 + m0 + quad * 4 + r] * 64.0f;
    }
    __syncthreads();   // W staged before first proj

    for (int tile = chunk; tile < NTILES; tile += NCHUNK) {
        // ---- proj: tokens m0..m0+15 x feats 0..63, K=64 (W frags from LDS) ----
        f32x4 ak[4], av[4];
        #pragma unroll
        for (int nt = 0; nt < 4; ++nt) {
            short8 bk0 = *(const short8*)&wkl[(nt * 2 + 0) * 512 + lane * 8];
            short8 bk1 = *(const short8*)&wkl[(nt * 2 + 1) * 512 + lane * 8];
            f32x4 z = {0.f, 0.f, 0.f, 0.f};
            z = __builtin_amdgcn_mfma_f32_16x16x32_bf16(a0, bk0, z, 0, 0, 0);
            ak[nt] = __builtin_amdgcn_mfma_f32_16x16x32_bf16(a1, bk1, z, 0, 0, 0);
            short8 bv0 = *(const short8*)&wvl[(nt * 2 + 0) * 512 + lane * 8];
            short8 bv1 = *(const short8*)&wvl[(nt * 2 + 1) * 512 + lane * 8];
            f32x4 y = {0.f, 0.f, 0.f, 0.f};
            y = __builtin_amdgcn_mfma_f32_16x16x32_bf16(a0, bv0, y, 0, 0, 0);
            av[nt] = __builtin_amdgcn_mfma_f32_16x16x32_bf16(a1, bv1, y, 0, 0, 0);
        }

        // ---- RoPE trig from current pos (before prefetch clobbers tp) ----
        float cl[4], sl[4], ch[4], sh[4];
        #pragma unroll
        for (int r = 0; r < 4; ++r) {
            float al = tp[r] * invf_lo, ah = tp[r] * invf_hi;
            cl[r] = __cosf(al); sl[r] = __sinf(al);
            ch[r] = __cosf(ah); sh[r] = __sinf(ah);
        }

        // ---- prefetch next tile's A-frags + pos (covered by LN/rope/kv) ----
        const int tn = tile + NCHUNK;
        if (tn < NTILES) {
            int tb = tn * 4 + w;
            const unsigned short* xb = xblob + (size_t)((b * 1024 + tb) * 2) * 512 + lane * 8;
            a0 = *(const short8*)&xb[0];
            a1 = *(const short8*)&xb[512];
            #pragma unroll
            for (int r = 0; r < 4; ++r)
                tp[r] = pos[(size_t)b * N_ + tn * 64 + m0 + quad * 4 + r] * 64.0f;
        }
        __builtin_amdgcn_sched_barrier(0);   // pin: prefetch issues HERE

        // ---- LN per token (row = quad*4+r); DPP reductions, in-place ----
        #pragma unroll
        for (int r = 0; r < 4; ++r) {
            float sk  = ak[0][r] + ak[1][r] + ak[2][r] + ak[3][r];
            float sk2 = ak[0][r]*ak[0][r] + ak[1][r]*ak[1][r] + ak[2][r]*ak[2][r] + ak[3][r]*ak[3][r];
            float sv  = av[0][r] + av[1][r] + av[2][r] + av[3][r];
            float sv2 = av[0][r]*av[0][r] + av[1][r]*av[1][r] + av[2][r]*av[2][r] + av[3][r]*av[3][r];
            sk = rowsum16(sk); sk2 = rowsum16(sk2);
            sv = rowsum16(sv); sv2 = rowsum16(sv2);
            float mk = sk * (1.0f / 64.0f);
            float rk = rsqrtf(sk2 * (1.0f / 64.0f) - mk * mk + 1e-5f);
            float mv = sv * (1.0f / 64.0f);
            float rv = rsqrtf(sv2 * (1.0f / 64.0f) - mv * mv + 1e-5f);
            #pragma unroll
            for (int nt = 0; nt < 4; ++nt) {
                ak[nt][r] = (ak[nt][r] - mk) * rk;
                av[nt][r] = (av[nt][r] - mv) * rv;
            }
        }

        // ---- RoPE(k): feat=16nt+c; partner feat^32 = tile nt^2, same lane ----
        #pragma unroll
        for (int r = 0; r < 4; ++r) {
            float lo0 = ak[0][r], hi0 = ak[2][r];
            ak[0][r] = lo0 * cl[r] - hi0 * sl[r];
            ak[2][r] = hi0 * cl[r] + lo0 * sl[r];
            float lo1 = ak[1][r], hi1 = ak[3][r];
            ak[1][r] = lo1 * ch[r] - hi1 * sh[r];
            ak[3][r] = hi1 * ch[r] + lo1 * sh[r];
        }

        // ---- barrier A: prev tile's kv-reads drained before overwrite ----
        __syncthreads();

        // ---- pack via cvt_pk (hw RNE), store transposed [feat][tok] ----
        #pragma unroll
        for (int nt = 0; nt < 4; ++nt) {
            uint32x2 kk, vv;
            kk[0] = cvtpk(ak[nt][0], ak[nt][1]);
            kk[1] = cvtpk(ak[nt][2], ak[nt][3]);
            vv[0] = cvtpk(av[nt][0], av[nt][1]);
            vv[1] = cvtpk(av[nt][2], av[nt][3]);
            *(uint32x2*)&kbuf[(nt * 16 + c) * 72 + m0 + quad * 4] = kk;
            *(uint32x2*)&vbuf[(nt * 16 + c) * 72 + m0 + quad * 4] = vv;
        }
        __syncthreads();   // barrier B: writes visible

        // ---- kv += k^T v : wave's d-band = 16w..16w+15, K = 64 toks ----
        short8 ka0 = *(const short8*)&kbuf[(m0 + c) * 72 + quad * 8];
        short8 ka1 = *(const short8*)&kbuf[(m0 + c) * 72 + 32 + quad * 8];
        #pragma unroll
        for (int nt = 0; nt < 4; ++nt) {
            short8 vb0 = *(const short8*)&vbuf[(nt * 16 + c) * 72 + quad * 8];
            short8 vb1 = *(const short8*)&vbuf[(nt * 16 + c) * 72 + 32 + quad * 8];
            akv[nt] = __builtin_amdgcn_mfma_f32_16x16x32_bf16(ka0, vb0, akv[nt], 0, 0, 0);
            akv[nt] = __builtin_amdgcn_mfma_f32_16x16x32_bf16(ka1, vb1, akv[nt], 0, 0, 0);
        }
    }

    // ---- plain stores of the partial kv (no atomics) ----
    float* dst = kv_part + ((size_t)(b * H_ + h) * NCHUNK + chunk) * 4096;
    #pragma unroll
    for (int nt = 0; nt < 4; ++nt)
        #pragma unroll
        for (int r = 0; r < 4; ++r)
            dst[(size_t)(16 * w + quad * 4 + r) * 64 + nt * 16 + c] = akv[nt][r];
}

// ---------------------------------------------------------------------------
// Kernel 2: reduce NCHUNK kv partials, M = (1/N) kv @ Wo_h, emit bf16
// B-fragment blobs.
// ---------------------------------------------------------------------------
__global__ __launch_bounds__(256) void k_m(
    const float* __restrict__ kv_part,
    const float* __restrict__ Wo,
    unsigned short* __restrict__ MTB)
{
    const int h = blockIdx.x, b = blockIdx.y;
    const int tid = threadIdx.x;
    __shared__ float kvs[64 * 65];
    __shared__ float wos[64 * 68];

    const float* src = kv_part + (size_t)(b * H_ + h) * NCHUNK * 4096;
    for (int i = tid; i < 4096; i += 256) {
        float s = 0.f;
        #pragma unroll 8
        for (int ch = 0; ch < NCHUNK; ++ch) s += src[ch * 4096 + i];
        kvs[(i >> 6) * 65 + (i & 63)] = s;
    }
    for (int i = tid; i < 1024; i += 256) {
        int dp = i >> 4, j4 = (i & 15) * 4;
        *(float4*)&wos[dp * 68 + j4] = *(const float4*)&Wo[(size_t)(h * 64 + dp) * 64 + j4];
    }
    __syncthreads();

    const int j0 = (tid & 15) * 4, d0 = (tid >> 4) * 4;
    float acc[4][4] = {{0.f}};
    #pragma unroll 4
    for (int dp = 0; dp < 64; ++dp) {
        float a_[4];
        #pragma unroll
        for (int i = 0; i < 4; ++i) a_[i] = kvs[(d0 + i) * 65 + dp];
        float4 w4 = *(const float4*)&wos[dp * 68 + j0];
        float w_[4] = {w4.x, w4.y, w4.z, w4.w};
        #pragma unroll
        for (int i = 0; i < 4; ++i)
            #pragma unroll
            for (int j = 0; j < 4; ++j)
                acc[i][j] += a_[i] * w_[j];
    }
    const float inv_n = 1.0f / (float)N_;
    unsigned short* dst = MTB + (size_t)(b * H_ + h) * 4096;
    #pragma unroll
    for (int i = 0; i < 4; ++i)
        #pragma unroll
        for (int j = 0; j < 4; ++j) {
            int d = d0 + i, jj = j0 + j;
            int nt = jj >> 4, cc = jj & 15;
            int half = d >> 5, qd = (d >> 3) & 3, e = d & 7;
            dst[(((nt * 2 + half) * 64 + qd * 16 + cc) * 8) + e] = f2b(acc[i][j] * inv_n);
        }
}

// ---------------------------------------------------------------------------
// Kernel 3 (MFMA): out[b,n,:] = sum_h rope(x@Wq_h) @ M[b,h]   grid (N/64, B).
// EXACT R5 form (the 151 µs config): 1 tile/block, bound(256,2), register-
// pipelined W/Mt, zero barriers (qbuf wave-local). R7 isolated the 2-tile
// variant as a ~11 µs regression -> reverted.
// ---------------------------------------------------------------------------
__global__ __launch_bounds__(256, 2) void k_out(
    const unsigned short* __restrict__ xblob,
    const float* __restrict__ pos,
    const unsigned short* __restrict__ WqB,
    const unsigned short* __restrict__ MTB,
    float* __restrict__ out)
{
    const int b = blockIdx.y;
    const int n0 = blockIdx.x * 64;
    const int tid  = threadIdx.x;
    const int lane = tid & 63;
    const int w    = tid >> 6;
    const int c    = lane & 15;
    const int quad = lane >> 4;
    const int m0   = w * 16;          // wave's 16-token band

    __shared__ unsigned short qbuf[64 * 72];   // q_rope bf16 [tok][feat] (wave-local bands)

    // ---- issue A-frags + h=0 B-frags immediately ----
    const int tb = blockIdx.x * 4 + w;
    const unsigned short* xb = xblob + (size_t)((b * 1024 + tb) * 2) * 512 + lane * 8;
    short8 a0 = *(const short8*)&xb[0];
    short8 a1 = *(const short8*)&xb[512];

    const unsigned short* wq0 = WqB + (size_t)lane * 8;
    const unsigned short* mt0 = MTB + (size_t)(b * H_) * 4096 + (size_t)lane * 8;
    short8 W[8], Mt[8];
    #pragma unroll
    for (int fr = 0; fr < 8; ++fr) W[fr]  = *(const short8*)&wq0[fr * 512];
    #pragma unroll
    for (int fr = 0; fr < 8; ++fr) Mt[fr] = *(const short8*)&mt0[fr * 512];
    __builtin_amdgcn_sched_barrier(0);   // pin: h=0 loads issue HERE

    // ---- RoPE trig (overlaps the loads above) ----
    const float invf_lo = exp2f(-0.4152410118609203f * (float)c);
    const float invf_hi = invf_lo * 0.01f;
    float csl[4], snl[4], csh[4], snh[4];
    #pragma unroll
    for (int r = 0; r < 4; ++r) {
        float tpv = pos[(size_t)b * N_ + n0 + m0 + quad * 4 + r] * 64.0f;
        float al = tpv * invf_lo, ah = tpv * invf_hi;
        csl[r] = __cosf(al); snl[r] = __sinf(al);
        csh[r] = __cosf(ah); snh[r] = __sinf(ah);
    }

    f32x4 oacc[4];
    #pragma unroll
    for (int nt = 0; nt < 4; ++nt) oacc[nt] = (f32x4){0.f, 0.f, 0.f, 0.f};

    #pragma unroll
    for (int h = 0; h < H_; ++h) {
        // ---- q proj: D[tok=quad*4+r][feat=nt*16+c] (consumes W) ----
        f32x4 aq[4];
        #pragma unroll
        for (int nt = 0; nt < 4; ++nt) {
            f32x4 z = {0.f, 0.f, 0.f, 0.f};
            z = __builtin_amdgcn_mfma_f32_16x16x32_bf16(a0, W[nt * 2 + 0], z, 0, 0, 0);
            aq[nt] = __builtin_amdgcn_mfma_f32_16x16x32_bf16(a1, W[nt * 2 + 1], z, 0, 0, 0);
        }

        // ---- prefetch W for h+1 (covered by rope+PV) ----
        if (h < H_ - 1) {
            #pragma unroll
            for (int fr = 0; fr < 8; ++fr)
                W[fr] = *(const short8*)&wq0[(size_t)(h + 1) * 4096 + fr * 512];
        }
        __builtin_amdgcn_sched_barrier(0);   // pin: W(h+1) issues HERE

        // ---- RoPE(q): partner feat^32 = tile nt^2, same lane ----
        #pragma unroll
        for (int r = 0; r < 4; ++r) {
            float lo0 = aq[0][r], hi0 = aq[2][r];
            aq[0][r] = lo0 * csl[r] - hi0 * snl[r];
            aq[2][r] = hi0 * csl[r] + lo0 * snl[r];
            float lo1 = aq[1][r], hi1 = aq[3][r];
            aq[1][r] = lo1 * csh[r] - hi1 * snh[r];
            aq[3][r] = hi1 * csh[r] + lo1 * snh[r];
        }

        // ---- pack q_rope -> qbuf [tok][feat] via cvt_pk; wave-local ----
        #pragma unroll
        for (int nt = 0; nt < 4; ++nt) {
            unsigned q01 = cvtpk(aq[nt][0], aq[nt][1]);
            unsigned q23 = cvtpk(aq[nt][2], aq[nt][3]);
            int base = (m0 + quad * 4) * 72 + nt * 16 + c;
            qbuf[base]       = (unsigned short)q01;
            qbuf[base + 72]  = (unsigned short)(q01 >> 16);
            qbuf[base + 144] = (unsigned short)q23;
            qbuf[base + 216] = (unsigned short)(q23 >> 16);
        }

        // ---- out += q_rope @ M_h : D[tok][j=nt*16+c] (consumes Mt) ----
        short8 qa0 = *(const short8*)&qbuf[(m0 + c) * 72 + quad * 8];
        short8 qa1 = *(const short8*)&qbuf[(m0 + c) * 72 + 32 + quad * 8];
        #pragma unroll
        for (int nt = 0; nt < 4; ++nt) {
            oacc[nt] = __builtin_amdgcn_mfma_f32_16x16x32_bf16(qa0, Mt[nt * 2 + 0], oacc[nt], 0, 0, 0);
            oacc[nt] = __builtin_amdgcn_mfma_f32_16x16x32_bf16(qa1, Mt[nt * 2 + 1], oacc[nt], 0, 0, 0);
        }

        // ---- prefetch Mt for h+1 (covered by next q-proj) ----
        if (h < H_ - 1) {
            #pragma unroll
            for (int fr = 0; fr < 8; ++fr)
                Mt[fr] = *(const short8*)&mt0[(size_t)(h + 1) * 4096 + fr * 512];
        }
        __builtin_amdgcn_sched_barrier(0);   // pin: Mt(h+1) issues HERE
    }

    // ---- store: out[tok][j], tok = m0+quad*4+r, j = nt*16+c ----
    #pragma unroll
    for (int nt = 0; nt < 4; ++nt)
        #pragma unroll
        for (int r = 0; r < 4; ++r)
            out[(size_t)(b * N_ + n0 + m0 + quad * 4 + r) * 64 + nt * 16 + c] = oacc[nt][r];
}

// ---------------------------------------------------------------------------
extern "C" void kernel_launch(void* const* d_in, const int* in_sizes, int n_in,
                              void* d_out, int out_size, void* d_ws, size_t ws_size,
                              hipStream_t stream)
{
    const float* x   = (const float*)d_in[0];
    const float* pos = (const float*)d_in[1];
    const float* Wq  = (const float*)d_in[2];
    const float* Wk  = (const float*)d_in[3];
    const float* Wv  = (const float*)d_in[4];
    const float* Wo  = (const float*)d_in[5];
    float* out = (float*)d_out;

    char* ws = (char*)d_ws;
    float* kv_part        = (float*)ws;                         // B*H*32*16KB = 16 MB
    unsigned short* MTB   = (unsigned short*)(ws + 16777216);   // 256 KB
    unsigned short* WqB   = (unsigned short*)(ws + 17039360);   // 64 KB
    unsigned short* WkB   = (unsigned short*)(ws + 17104896);   // 64 KB
    unsigned short* WvB   = (unsigned short*)(ws + 17170432);   // 64 KB
    unsigned short* xblob = (unsigned short*)(ws + 17235968);   // 8.4 MB

    k_prep<<<dim3(2432), 256, 0, stream>>>(x, Wq, Wk, Wv,
                                           WqB, WkB, WvB, xblob);
    k_kv  <<<dim3(NCHUNK, H_, B_), 256, 0, stream>>>(xblob, pos, WkB, WvB, kv_part);
    k_m   <<<dim3(H_, B_), 256, 0, stream>>>(kv_part, Wo, MTB);
    k_out <<<dim3(NTILES, B_), 256, 0, stream>>>(xblob, pos, WqB, MTB, out);
}

// Round 9
// 141.994 us; speedup vs baseline: 1.1419x; 1.1419x over previous
//
#include <hip/hip_runtime.h>

#define B_ 4
#define N_ 16384
#define D_ 64
#define H_ 8
#define E_ 512
#define NCHUNK 32
#define NTILES (N_ / 64)

typedef __attribute__((ext_vector_type(8))) short short8;
typedef __attribute__((ext_vector_type(4))) float f32x4;
typedef __attribute__((ext_vector_type(2))) unsigned int uint32x2;

// f32 -> bf16 (RNE), scalar path (prep kernels only)
__device__ __forceinline__ unsigned short f2b(float f) {
    unsigned u = __float_as_uint(f);
    return (unsigned short)((u + 0x7fffu + ((u >> 16) & 1u)) >> 16);
}

// packed f32x2 -> bf16x2 (hardware RNE): lo16 = cvt(a), hi16 = cvt(b)
__device__ __forceinline__ unsigned cvtpk(float a, float b) {
    unsigned r;
    asm("v_cvt_pk_bf16_f32 %0, %1, %2" : "=v"(r) : "v"(a), "v"(b));
    return r;
}

// 16-lane sum via VALU DPP butterfly (no DS pipe)
template<int CTRL>
__device__ __forceinline__ float dppadd(float x) {
    int y = __builtin_amdgcn_update_dpp(0, __float_as_int(x), CTRL, 0xF, 0xF, true);
    return x + __int_as_float(y);
}
__device__ __forceinline__ float rowsum16(float x) {
    x = dppadd<0xB1>(x);    // quad_perm xor1
    x = dppadd<0x4E>(x);    // quad_perm xor2
    x = dppadd<0x141>(x);   // row_half_mirror
    x = dppadd<0x140>(x);   // row_mirror
    return x;
}

// ---------------------------------------------------------------------------
// k_prep: fused {pack Wq/Wk/Wv blobs | pack x blob}.
//   bid [0,384):  W blobs — per head [fr=nt*2+half][lane][e] u16 (8KB/head);
//                 element = W[kin][h*64+feat]; feat=nt*16+(lane&15),
//                 kin = half*32 + (lane>>4)*8 + e.
//   bid [384,2432): x blob — ((b*1024+tb)*2+fr)*512 + lane*8 + e with
//                 element = x[b][tb*16+(lane&15)][fr*32+(lane>>4)*8+e].
// ---------------------------------------------------------------------------
__global__ __launch_bounds__(256) void k_prep(
    const float* __restrict__ x,
    const float* __restrict__ Wq, const float* __restrict__ Wk,
    const float* __restrict__ Wv,
    unsigned short* __restrict__ WqB, unsigned short* __restrict__ WkB,
    unsigned short* __restrict__ WvB,
    unsigned short* __restrict__ xblob)
{
    const int bid = blockIdx.x, tid = threadIdx.x;
    if (bid < 384) {
        int mat = bid >> 7, sub = bid & 127;
        const float* src = (mat == 0) ? Wq : (mat == 1) ? Wk : Wv;
        unsigned short* dst = (mat == 0) ? WqB : (mat == 1) ? WkB : WvB;
        int id = sub * 256 + tid;          // 0..32767
        int kin = id >> 9, f = id & 511;
        int h = f >> 6, feat = f & 63;
        int nt = feat >> 4, cc = feat & 15;
        int half = kin >> 5, qd = (kin >> 3) & 3, e = kin & 7;
        dst[(size_t)h * 4096 + (((nt * 2 + half) * 64 + qd * 16 + cc) * 8) + e]
            = f2b(src[id]);
        return;
    }
    int idx = (bid - 384) * 256 + tid;     // 0..524287
    int lane = idx & 63, fr = (idx >> 6) & 1, tb = (idx >> 7) & 1023, b = idx >> 17;
    int cc = lane & 15, qd = lane >> 4;
    const float* src = &x[((size_t)b * N_ + tb * 16 + cc) * 64 + fr * 32 + qd * 8];
    float4 v0 = *(const float4*)src;
    float4 v1 = *(const float4*)(src + 4);
    ushort4 u0, u1;
    u0.x = f2b(v0.x); u0.y = f2b(v0.y); u0.z = f2b(v0.z); u0.w = f2b(v0.w);
    u1.x = f2b(v1.x); u1.y = f2b(v1.y); u1.z = f2b(v1.z); u1.w = f2b(v1.w);
    *(ushort4*)&xblob[(size_t)idx * 8]     = u0;
    *(ushort4*)&xblob[(size_t)idx * 8 + 4] = u1;
}

// ---------------------------------------------------------------------------
// Kernel 1 (MFMA): k,v projection + LN + RoPE(k) + kv partial accumulation.
// grid (NCHUNK=32, H, B) = 1024 blocks @ bound(256,4).
// W fragments in LDS (staged once/block; LDS-held state is immune to the
// R4/R6 remat-from-HBM bug — verified R8: VGPR 64, FETCH 4.8 MB, occ 27.5%).
// LDS 34.8 KB -> 4 blocks/CU, one grid round. 8 tiles/block, no atomics.
// ---------------------------------------------------------------------------
__global__ __launch_bounds__(256, 4) void k_kv(
    const unsigned short* __restrict__ xblob,
    const float* __restrict__ pos,
    const unsigned short* __restrict__ WkB,
    const unsigned short* __restrict__ WvB,
    float* __restrict__ kv_part)
{
    const int b = blockIdx.z, h = blockIdx.y, chunk = blockIdx.x;
    const int tid  = threadIdx.x;
    const int lane = tid & 63;
    const int w    = tid >> 6;        // wave id 0..3
    const int c    = lane & 15;
    const int quad = lane >> 4;
    const int m0   = w * 16;          // wave's 16-row band

    __shared__ unsigned short kbuf[64 * 72];   // k bf16 [feat][tok]  (9.2 KB)
    __shared__ unsigned short vbuf[64 * 72];   // v bf16 [feat][tok]  (9.2 KB)
    __shared__ unsigned short wkl[4096];       // Wk frag blob, head h (8 KB)
    __shared__ unsigned short wvl[4096];       // Wv frag blob, head h (8 KB)

    // ---- stage W blobs to LDS once (coop copy, already bf16 frag layout) ----
    {
        const float4* srcK = (const float4*)(WkB + (size_t)h * 4096);
        const float4* srcV = (const float4*)(WvB + (size_t)h * 4096);
        float4* dstK = (float4*)wkl;
        float4* dstV = (float4*)wvl;
        #pragma unroll
        for (int i = 0; i < 2; ++i) {       // 512 float4 per blob
            dstK[tid + i * 256] = srcK[tid + i * 256];
            dstV[tid + i * 256] = srcV[tid + i * 256];
        }
    }

    const float invf_lo = exp2f(-0.4152410118609203f * (float)c);  // 10000^(-c/32)
    const float invf_hi = invf_lo * 0.01f;                          // 10000^(-(16+c)/32)

    f32x4 akv[4];
    #pragma unroll
    for (int nt = 0; nt < 4; ++nt) akv[nt] = (f32x4){0.f, 0.f, 0.f, 0.f};

    // ---- prologue: first tile's A-frags + pos ----
    short8 a0, a1;
    float tp[4];
    {
        int tb = chunk * 4 + w;
        const unsigned short* xb = xblob + (size_t)((b * 1024 + tb) * 2) * 512 + lane * 8;
        a0 = *(const short8*)&xb[0];
        a1 = *(const short8*)&xb[512];
        #pragma unroll
        for (int r = 0; r < 4; ++r)
            tp[r] = pos[(size_t)b * N_ + chunk * 64 + m0 + quad * 4 + r] * 64.0f;
    }
    __syncthreads();   // W staged before first proj

    for (int tile = chunk; tile < NTILES; tile += NCHUNK) {
        // ---- proj: tokens m0..m0+15 x feats 0..63, K=64 (W frags from LDS) ----
        f32x4 ak[4], av[4];
        #pragma unroll
        for (int nt = 0; nt < 4; ++nt) {
            short8 bk0 = *(const short8*)&wkl[(nt * 2 + 0) * 512 + lane * 8];
            short8 bk1 = *(const short8*)&wkl[(nt * 2 + 1) * 512 + lane * 8];
            f32x4 z = {0.f, 0.f, 0.f, 0.f};
            z = __builtin_amdgcn_mfma_f32_16x16x32_bf16(a0, bk0, z, 0, 0, 0);
            ak[nt] = __builtin_amdgcn_mfma_f32_16x16x32_bf16(a1, bk1, z, 0, 0, 0);
            short8 bv0 = *(const short8*)&wvl[(nt * 2 + 0) * 512 + lane * 8];
            short8 bv1 = *(const short8*)&wvl[(nt * 2 + 1) * 512 + lane * 8];
            f32x4 y = {0.f, 0.f, 0.f, 0.f};
            y = __builtin_amdgcn_mfma_f32_16x16x32_bf16(a0, bv0, y, 0, 0, 0);
            av[nt] = __builtin_amdgcn_mfma_f32_16x16x32_bf16(a1, bv1, y, 0, 0, 0);
        }

        // ---- RoPE trig from current pos (before prefetch clobbers tp) ----
        float cl[4], sl[4], ch[4], sh[4];
        #pragma unroll
        for (int r = 0; r < 4; ++r) {
            float al = tp[r] * invf_lo, ah = tp[r] * invf_hi;
            cl[r] = __cosf(al); sl[r] = __sinf(al);
            ch[r] = __cosf(ah); sh[r] = __sinf(ah);
        }

        // ---- prefetch next tile's A-frags + pos (covered by LN/rope/kv) ----
        const int tn = tile + NCHUNK;
        if (tn < NTILES) {
            int tb = tn * 4 + w;
            const unsigned short* xb = xblob + (size_t)((b * 1024 + tb) * 2) * 512 + lane * 8;
            a0 = *(const short8*)&xb[0];
            a1 = *(const short8*)&xb[512];
            #pragma unroll
            for (int r = 0; r < 4; ++r)
                tp[r] = pos[(size_t)b * N_ + tn * 64 + m0 + quad * 4 + r] * 64.0f;
        }
        __builtin_amdgcn_sched_barrier(0);   // pin: prefetch issues HERE

        // ---- LN per token (row = quad*4+r); DPP reductions, in-place ----
        #pragma unroll
        for (int r = 0; r < 4; ++r) {
            float sk  = ak[0][r] + ak[1][r] + ak[2][r] + ak[3][r];
            float sk2 = ak[0][r]*ak[0][r] + ak[1][r]*ak[1][r] + ak[2][r]*ak[2][r] + ak[3][r]*ak[3][r];
            float sv  = av[0][r] + av[1][r] + av[2][r] + av[3][r];
            float sv2 = av[0][r]*av[0][r] + av[1][r]*av[1][r] + av[2][r]*av[2][r] + av[3][r]*av[3][r];
            sk = rowsum16(sk); sk2 = rowsum16(sk2);
            sv = rowsum16(sv); sv2 = rowsum16(sv2);
            float mk = sk * (1.0f / 64.0f);
            float rk = rsqrtf(sk2 * (1.0f / 64.0f) - mk * mk + 1e-5f);
            float mv = sv * (1.0f / 64.0f);
            float rv = rsqrtf(sv2 * (1.0f / 64.0f) - mv * mv + 1e-5f);
            #pragma unroll
            for (int nt = 0; nt < 4; ++nt) {
                ak[nt][r] = (ak[nt][r] - mk) * rk;
                av[nt][r] = (av[nt][r] - mv) * rv;
            }
        }

        // ---- RoPE(k): feat=16nt+c; partner feat^32 = tile nt^2, same lane ----
        #pragma unroll
        for (int r = 0; r < 4; ++r) {
            float lo0 = ak[0][r], hi0 = ak[2][r];
            ak[0][r] = lo0 * cl[r] - hi0 * sl[r];
            ak[2][r] = hi0 * cl[r] + lo0 * sl[r];
            float lo1 = ak[1][r], hi1 = ak[3][r];
            ak[1][r] = lo1 * ch[r] - hi1 * sh[r];
            ak[3][r] = hi1 * ch[r] + lo1 * sh[r];
        }

        // ---- barrier A: prev tile's kv-reads drained before overwrite ----
        __syncthreads();

        // ---- pack via cvt_pk (hw RNE), store transposed [feat][tok] ----
        #pragma unroll
        for (int nt = 0; nt < 4; ++nt) {
            uint32x2 kk, vv;
            kk[0] = cvtpk(ak[nt][0], ak[nt][1]);
            kk[1] = cvtpk(ak[nt][2], ak[nt][3]);
            vv[0] = cvtpk(av[nt][0], av[nt][1]);
            vv[1] = cvtpk(av[nt][2], av[nt][3]);
            *(uint32x2*)&kbuf[(nt * 16 + c) * 72 + m0 + quad * 4] = kk;
            *(uint32x2*)&vbuf[(nt * 16 + c) * 72 + m0 + quad * 4] = vv;
        }
        __syncthreads();   // barrier B: writes visible

        // ---- kv += k^T v : wave's d-band = 16w..16w+15, K = 64 toks ----
        short8 ka0 = *(const short8*)&kbuf[(m0 + c) * 72 + quad * 8];
        short8 ka1 = *(const short8*)&kbuf[(m0 + c) * 72 + 32 + quad * 8];
        #pragma unroll
        for (int nt = 0; nt < 4; ++nt) {
            short8 vb0 = *(const short8*)&vbuf[(nt * 16 + c) * 72 + quad * 8];
            short8 vb1 = *(const short8*)&vbuf[(nt * 16 + c) * 72 + 32 + quad * 8];
            akv[nt] = __builtin_amdgcn_mfma_f32_16x16x32_bf16(ka0, vb0, akv[nt], 0, 0, 0);
            akv[nt] = __builtin_amdgcn_mfma_f32_16x16x32_bf16(ka1, vb1, akv[nt], 0, 0, 0);
        }
    }

    // ---- plain stores of the partial kv (no atomics) ----
    float* dst = kv_part + ((size_t)(b * H_ + h) * NCHUNK + chunk) * 4096;
    #pragma unroll
    for (int nt = 0; nt < 4; ++nt)
        #pragma unroll
        for (int r = 0; r < 4; ++r)
            dst[(size_t)(16 * w + quad * 4 + r) * 64 + nt * 16 + c] = akv[nt][r];
}

// ---------------------------------------------------------------------------
// Kernel 2: reduce NCHUNK kv partials + M = (1/N) kv @ Wo_h, d-SLICED:
// grid (H, B, 8) = 256 blocks; slice s owns d-rows [s*8, s*8+8).
// (R8's 32-block k_m serially streamed 16 MB on 1/8 of the chip — the
// contraction is over e, so d-rows split cleanly.) Blob emit: half=s>>2,
// qd=s&3, e=d&7 are slice-constant.
// ---------------------------------------------------------------------------
__global__ __launch_bounds__(256) void k_m(
    const float* __restrict__ kv_part,
    const float* __restrict__ Wo,
    unsigned short* __restrict__ MTB)
{
    const int h = blockIdx.x, b = blockIdx.y, s = blockIdx.z;
    const int tid = threadIdx.x;
    __shared__ float kvs[8 * 65];
    __shared__ float wos[64 * 68];

    const float* src = kv_part + (size_t)(b * H_ + h) * NCHUNK * 4096 + s * 512;
    #pragma unroll
    for (int k = 0; k < 2; ++k) {
        int idx = tid + k * 256;           // 0..511 within slice (d_local*64 + e)
        float ssum = 0.f;
        #pragma unroll 8
        for (int ch = 0; ch < NCHUNK; ++ch) ssum += src[(size_t)ch * 4096 + idx];
        kvs[(idx >> 6) * 65 + (idx & 63)] = ssum;
    }
    for (int i = tid; i < 1024; i += 256) {
        int dp = i >> 4, j4 = (i & 15) * 4;
        *(float4*)&wos[dp * 68 + j4] = *(const float4*)&Wo[(size_t)(h * 64 + dp) * 64 + j4];
    }
    __syncthreads();

    const float inv_n = 1.0f / (float)N_;
    unsigned short* dst = MTB + (size_t)(b * H_ + h) * 4096;
    const int half = s >> 2, qd = s & 3;
    #pragma unroll
    for (int k = 0; k < 2; ++k) {
        int idx = tid + k * 256;
        int dl = idx >> 6, j = idx & 63;   // dl = d_local (= d&7), j = out col
        float acc = 0.f;
        #pragma unroll 8
        for (int e = 0; e < 64; ++e)
            acc += kvs[dl * 65 + e] * wos[e * 68 + j];
        int nt = j >> 4, cc = j & 15;
        dst[(((nt * 2 + half) * 64 + qd * 16 + cc) * 8) + dl] = f2b(acc * inv_n);
    }
}

// ---------------------------------------------------------------------------
// Kernel 3 (MFMA): out[b,n,:] = sum_h rope(x@Wq_h) @ M[b,h]   grid (N/64, B).
// R5 structure; bound (256,3): cap 170 VGPR holds the ~130 live pipeline
// regs (W[8]+Mt[8]+oacc+aq+trig) -> 3 blocks/CU vs 2 (1024 blocks ran two
// residency rounds at bound 2). sched_barrier pins guard the pipeline.
// FALSIFIER: k_out in top-5 with VGPR<=64 => de-pipelined, revert to 2.
// ---------------------------------------------------------------------------
__global__ __launch_bounds__(256, 3) void k_out(
    const unsigned short* __restrict__ xblob,
    const float* __restrict__ pos,
    const unsigned short* __restrict__ WqB,
    const unsigned short* __restrict__ MTB,
    float* __restrict__ out)
{
    const int b = blockIdx.y;
    const int n0 = blockIdx.x * 64;
    const int tid  = threadIdx.x;
    const int lane = tid & 63;
    const int w    = tid >> 6;
    const int c    = lane & 15;
    const int quad = lane >> 4;
    const int m0   = w * 16;          // wave's 16-token band

    __shared__ unsigned short qbuf[64 * 72];   // q_rope bf16 [tok][feat] (wave-local bands)

    // ---- issue A-frags + h=0 B-frags immediately ----
    const int tb = blockIdx.x * 4 + w;
    const unsigned short* xb = xblob + (size_t)((b * 1024 + tb) * 2) * 512 + lane * 8;
    short8 a0 = *(const short8*)&xb[0];
    short8 a1 = *(const short8*)&xb[512];

    const unsigned short* wq0 = WqB + (size_t)lane * 8;
    const unsigned short* mt0 = MTB + (size_t)(b * H_) * 4096 + (size_t)lane * 8;
    short8 W[8], Mt[8];
    #pragma unroll
    for (int fr = 0; fr < 8; ++fr) W[fr]  = *(const short8*)&wq0[fr * 512];
    #pragma unroll
    for (int fr = 0; fr < 8; ++fr) Mt[fr] = *(const short8*)&mt0[fr * 512];
    __builtin_amdgcn_sched_barrier(0);   // pin: h=0 loads issue HERE

    // ---- RoPE trig (overlaps the loads above) ----
    const float invf_lo = exp2f(-0.4152410118609203f * (float)c);
    const float invf_hi = invf_lo * 0.01f;
    float csl[4], snl[4], csh[4], snh[4];
    #pragma unroll
    for (int r = 0; r < 4; ++r) {
        float tpv = pos[(size_t)b * N_ + n0 + m0 + quad * 4 + r] * 64.0f;
        float al = tpv * invf_lo, ah = tpv * invf_hi;
        csl[r] = __cosf(al); snl[r] = __sinf(al);
        csh[r] = __cosf(ah); snh[r] = __sinf(ah);
    }

    f32x4 oacc[4];
    #pragma unroll
    for (int nt = 0; nt < 4; ++nt) oacc[nt] = (f32x4){0.f, 0.f, 0.f, 0.f};

    #pragma unroll
    for (int h = 0; h < H_; ++h) {
        // ---- q proj: D[tok=quad*4+r][feat=nt*16+c] (consumes W) ----
        f32x4 aq[4];
        #pragma unroll
        for (int nt = 0; nt < 4; ++nt) {
            f32x4 z = {0.f, 0.f, 0.f, 0.f};
            z = __builtin_amdgcn_mfma_f32_16x16x32_bf16(a0, W[nt * 2 + 0], z, 0, 0, 0);
            aq[nt] = __builtin_amdgcn_mfma_f32_16x16x32_bf16(a1, W[nt * 2 + 1], z, 0, 0, 0);
        }

        // ---- prefetch W for h+1 (covered by rope+PV) ----
        if (h < H_ - 1) {
            #pragma unroll
            for (int fr = 0; fr < 8; ++fr)
                W[fr] = *(const short8*)&wq0[(size_t)(h + 1) * 4096 + fr * 512];
        }
        __builtin_amdgcn_sched_barrier(0);   // pin: W(h+1) issues HERE

        // ---- RoPE(q): partner feat^32 = tile nt^2, same lane ----
        #pragma unroll
        for (int r = 0; r < 4; ++r) {
            float lo0 = aq[0][r], hi0 = aq[2][r];
            aq[0][r] = lo0 * csl[r] - hi0 * snl[r];
            aq[2][r] = hi0 * csl[r] + lo0 * snl[r];
            float lo1 = aq[1][r], hi1 = aq[3][r];
            aq[1][r] = lo1 * csh[r] - hi1 * snh[r];
            aq[3][r] = hi1 * csh[r] + lo1 * snh[r];
        }

        // ---- pack q_rope -> qbuf [tok][feat] via cvt_pk; wave-local ----
        #pragma unroll
        for (int nt = 0; nt < 4; ++nt) {
            unsigned q01 = cvtpk(aq[nt][0], aq[nt][1]);
            unsigned q23 = cvtpk(aq[nt][2], aq[nt][3]);
            int base = (m0 + quad * 4) * 72 + nt * 16 + c;
            qbuf[base]       = (unsigned short)q01;
            qbuf[base + 72]  = (unsigned short)(q01 >> 16);
            qbuf[base + 144] = (unsigned short)q23;
            qbuf[base + 216] = (unsigned short)(q23 >> 16);
        }

        // ---- out += q_rope @ M_h : D[tok][j=nt*16+c] (consumes Mt) ----
        short8 qa0 = *(const short8*)&qbuf[(m0 + c) * 72 + quad * 8];
        short8 qa1 = *(const short8*)&qbuf[(m0 + c) * 72 + 32 + quad * 8];
        #pragma unroll
        for (int nt = 0; nt < 4; ++nt) {
            oacc[nt] = __builtin_amdgcn_mfma_f32_16x16x32_bf16(qa0, Mt[nt * 2 + 0], oacc[nt], 0, 0, 0);
            oacc[nt] = __builtin_amdgcn_mfma_f32_16x16x32_bf16(qa1, Mt[nt * 2 + 1], oacc[nt], 0, 0, 0);
        }

        // ---- prefetch Mt for h+1 (covered by next q-proj) ----
        if (h < H_ - 1) {
            #pragma unroll
            for (int fr = 0; fr < 8; ++fr)
                Mt[fr] = *(const short8*)&mt0[(size_t)(h + 1) * 4096 + fr * 512];
        }
        __builtin_amdgcn_sched_barrier(0);   // pin: Mt(h+1) issues HERE
    }

    // ---- store: out[tok][j], tok = m0+quad*4+r, j = nt*16+c ----
    #pragma unroll
    for (int nt = 0; nt < 4; ++nt)
        #pragma unroll
        for (int r = 0; r < 4; ++r)
            out[(size_t)(b * N_ + n0 + m0 + quad * 4 + r) * 64 + nt * 16 + c] = oacc[nt][r];
}

// ---------------------------------------------------------------------------
extern "C" void kernel_launch(void* const* d_in, const int* in_sizes, int n_in,
                              void* d_out, int out_size, void* d_ws, size_t ws_size,
                              hipStream_t stream)
{
    const float* x   = (const float*)d_in[0];
    const float* pos = (const float*)d_in[1];
    const float* Wq  = (const float*)d_in[2];
    const float* Wk  = (const float*)d_in[3];
    const float* Wv  = (const float*)d_in[4];
    const float* Wo  = (const float*)d_in[5];
    float* out = (float*)d_out;

    char* ws = (char*)d_ws;
    float* kv_part        = (float*)ws;                         // B*H*32*16KB = 16 MB
    unsigned short* MTB   = (unsigned short*)(ws + 16777216);   // 256 KB
    unsigned short* WqB   = (unsigned short*)(ws + 17039360);   // 64 KB
    unsigned short* WkB   = (unsigned short*)(ws + 17104896);   // 64 KB
    unsigned short* WvB   = (unsigned short*)(ws + 17170432);   // 64 KB
    unsigned short* xblob = (unsigned short*)(ws + 17235968);   // 8.4 MB

    k_prep<<<dim3(2432), 256, 0, stream>>>(x, Wq, Wk, Wv,
                                           WqB, WkB, WvB, xblob);
    k_kv  <<<dim3(NCHUNK, H_, B_), 256, 0, stream>>>(xblob, pos, WkB, WvB, kv_part);
    k_m   <<<dim3(H_, B_, 8), 256, 0, stream>>>(kv_part, Wo, MTB);
    k_out <<<dim3(NTILES, B_), 256, 0, stream>>>(xblob, pos, WqB, MTB, out);
}